// Round 20
// baseline (177.107 us; speedup 1.0000x reference)
//
#include <hip/hip_runtime.h>
#include <stdint.h>

#define M_TOTAL 32768   // B*T
#define NUMS    512
#define DIM     1024
#define TOPK    33

typedef __bf16 bf16_t;
typedef float  f32x4  __attribute__((ext_vector_type(4)));
typedef int    i32x4  __attribute__((ext_vector_type(4)));
typedef unsigned short ushort_t;
typedef unsigned char  uchar_t;

__device__ __forceinline__ uint32_t pk4_fp8(float a, float b, float c, float d) {
    uint32_t w = 0;
    w = __builtin_amdgcn_cvt_pk_fp8_f32(a, b, w, false);
    w = __builtin_amdgcn_cvt_pk_fp8_f32(c, d, w, true);
    return w;
}
__device__ __forceinline__ int q12(float w) {   // round(w*4096), clamp +-127
    int v = __float2int_rn(w * 4096.f);
    return v > 127 ? 127 : (v < -127 ? -127 : v);
}

#define GLDS16(g, l) __builtin_amdgcn_global_load_lds( \
    (const __attribute__((address_space(1))) void*)(g), \
    (__attribute__((address_space(3))) void*)(l), 16, 0, 0)

// ---------------------------------------------------------------------------
// cvtprep: blocks 0..511: mem fp32 -> memF8 e4m3 (x16) + memT8 i8 (x4096,
//   transposed), dispatched first so the LDS-transpose overlaps the stream.
// blocks 512..2559: data fp32 -> dataF8 e4m3 (XCD-aligned writes).
// ---------------------------------------------------------------------------
__global__ __launch_bounds__(256)
void cvtprep_kernel(const float* __restrict__ data, const float* __restrict__ mem,
                    uchar_t* __restrict__ dataF8, uchar_t* __restrict__ memF8,
                    char* __restrict__ memT8) {
    __shared__ float tile[32][33];
    const int bid = blockIdx.x;
    const int t   = threadIdx.x;
    if (bid < 512) {
        const int bi = bid & 15;       // k-block (NUMS/32)
        const int bj = bid >> 4;       // d-block (DIM/32)
        const int r  = t >> 3;
        const int c4 = (t & 7) * 4;
        const float4 v = *(const float4*)(mem + (size_t)(bi * 32 + r) * DIM + bj * 32 + c4);
        *(uint32_t*)(memF8 + (size_t)(bi * 32 + r) * DIM + bj * 32 + c4) =
            pk4_fp8(v.x * 16.f, v.y * 16.f, v.z * 16.f, v.w * 16.f);
        tile[r][c4 + 0] = v.x; tile[r][c4 + 1] = v.y;
        tile[r][c4 + 2] = v.z; tile[r][c4 + 3] = v.w;
        __syncthreads();
        const int q0 = q12(tile[c4 + 0][r]);
        const int q1 = q12(tile[c4 + 1][r]);
        const int q2 = q12(tile[c4 + 2][r]);
        const int q3 = q12(tile[c4 + 3][r]);
        char4 o; o.x = (char)q0; o.y = (char)q1; o.z = (char)q2; o.w = (char)q3;
        *(char4*)(memT8 + (size_t)(bj * 32 + r) * NUMS + bi * 32 + c4) = o;
    } else {
        const int db = bid - 512;
        const int x = db & 7;          // XCD
        const int j = db >> 3;         // 0..255
        size_t i = ((size_t)x * 4096 + (size_t)j * 16) * DIM + t * 8;
#pragma unroll
        for (int it = 0; it < 8; ++it, i += 2048) {
            const float4 v0 = *(const float4*)(data + i);
            const float4 v1 = *(const float4*)(data + i + 4);
            uint2 pk;
            pk.x = pk4_fp8(v0.x, v0.y, v0.z, v0.w);
            pk.y = pk4_fp8(v1.x, v1.y, v1.z, v1.w);
            *(uint2*)(dataF8 + i) = pk;
        }
    }
}

// ---------------------------------------------------------------------------
// G1 (fp8): att = sigmoid(dataF8 @ memF8^T / 512) -> i8 code att*254-127.
// 128x128 tile, K-slice 128 fp8 (8 steps), double-buffered 64KB LDS with
// counted vmcnt: STAGE(t+1) -> vmcnt(8) -> barrier -> COMP(t) -> barrier.
// 256 thr = 4 waves (2x2), 2 blocks/CU. (R18 core, best measured.)
// Blocks >= 1024: colsumF[d] = sum_k memT8[d][k] (rides on this launch;
// must precede g2).
// ---------------------------------------------------------------------------
__global__ __launch_bounds__(256, 2)
void g1_kernel(const uchar_t* __restrict__ dataF8,
               const uchar_t* __restrict__ memF8,
               const char* __restrict__ memT8,
               float* __restrict__ colsumF,
               char* __restrict__ att8) {
    __shared__ __align__(16) unsigned char smem[65536];
    const int t    = threadIdx.x;
    if (blockIdx.x >= 1024) {
        const int d = (blockIdx.x - 1024) * 256 + t;   // 0..1023
        const int* p = (const int*)(memT8 + (size_t)d * NUMS);
        int s = 0;
#pragma unroll
        for (int i = 0; i < 128; ++i) {
            const int w = p[i];
            s += (int)(char)(w) + (int)(char)(w >> 8)
               + (int)(char)(w >> 16) + (int)(char)(w >> 24);
        }
        colsumF[d] = (float)s;
        return;
    }
    const int lane = t & 63;
    const int wid  = t >> 6;
    const int wr   = wid >> 1;
    const int wc   = wid & 1;
    const int wg = (blockIdx.x & 7) * 128 + (blockIdx.x >> 3);
    const int m0 = (wg >> 2) * 128;
    const int n0 = (wg & 3) * 128;

    f32x4 zero = {0.f, 0.f, 0.f, 0.f};
    f32x4 acc[4][4];
#pragma unroll
    for (int m = 0; m < 4; ++m)
#pragma unroll
        for (int n = 0; n < 4; ++n) acc[m][n] = zero;

    const int srcoff = (((lane & 7) ^ (lane >> 3)) & 7) * 16;
    const uchar_t* aS = dataF8 + (size_t)(m0 + wid * 32 + (lane >> 3)) * DIM + srcoff;
    const uchar_t* bS = memF8  + (size_t)(n0 + wid * 32 + (lane >> 3)) * DIM + srcoff;

    const int q  = lane >> 4;
    const int o8 = (q & 1) * 8;

#define G1_STAGE(TT_, BOFF_) {                                                  \
        unsigned char* da = smem + (BOFF_) + wid * 4096 + lane * 16;            \
        unsigned char* db = da + 16384;                                         \
        const uchar_t* sa = aS + (TT_) * 128;                                   \
        const uchar_t* sb = bS + (TT_) * 128;                                   \
        GLDS16(sa,            da);        GLDS16(sb,            db);            \
        GLDS16(sa +  8 * DIM, da + 1024); GLDS16(sb +  8 * DIM, db + 1024);     \
        GLDS16(sa + 16 * DIM, da + 2048); GLDS16(sb + 16 * DIM, db + 2048);     \
        GLDS16(sa + 24 * DIM, da + 3072); GLDS16(sb + 24 * DIM, db + 3072); }

#define G1_COMP(BOFF_)                                                          \
    _Pragma("unroll") for (int ki = 0; ki < 4; ++ki) {                          \
        const int c16 = ki * 2 + (q >> 1);                                      \
        long af[4], bfr[4];                                                     \
        _Pragma("unroll") for (int m = 0; m < 4; ++m) {                         \
            const int row = wr * 64 + m * 16 + (lane & 15);                     \
            af[m] = *(const long*)(smem + (BOFF_) + row * 128                   \
                    + ((c16 ^ (row & 7)) << 4) + o8);                           \
        }                                                                       \
        _Pragma("unroll") for (int n = 0; n < 4; ++n) {                         \
            const int col = wc * 64 + n * 16 + (lane & 15);                     \
            bfr[n] = *(const long*)(smem + (BOFF_) + 16384 + col * 128          \
                    + ((c16 ^ (col & 7)) << 4) + o8);                           \
        }                                                                       \
        _Pragma("unroll") for (int m = 0; m < 4; ++m)                           \
            _Pragma("unroll") for (int n = 0; n < 4; ++n)                       \
                acc[m][n] = __builtin_amdgcn_mfma_f32_16x16x32_fp8_fp8(         \
                    af[m], bfr[n], acc[m][n], 0, 0, 0);                         \
    }

    G1_STAGE(0, 0)
    for (int tt = 0; tt < 8; ++tt) {
        if (tt < 7) {
            if ((tt & 1) == 0) G1_STAGE(tt + 1, 32768)
            else               G1_STAGE(tt + 1, 0)
            asm volatile("s_waitcnt vmcnt(8)" ::: "memory");
        } else {
            asm volatile("s_waitcnt vmcnt(0)" ::: "memory");
        }
        __builtin_amdgcn_s_barrier();
        __builtin_amdgcn_sched_barrier(0);
        __builtin_amdgcn_s_setprio(1);
        if ((tt & 1) == 0) G1_COMP(0)
        else               G1_COMP(32768)
        __builtin_amdgcn_s_setprio(0);
        __builtin_amdgcn_s_barrier();
    }
#undef G1_STAGE
#undef G1_COMP

    // ---- epilogue: sigmoid(acc/512) -> i8 codes, tile [128][128] in LDS
    char* lAtt = (char*)smem;
#pragma unroll
    for (int m = 0; m < 4; ++m)
#pragma unroll
        for (int n = 0; n < 4; ++n)
#pragma unroll
            for (int reg = 0; reg < 4; ++reg) {
                const int row = wr * 64 + m * 16 + (lane >> 4) * 4 + reg;
                const int col = wc * 64 + n * 16 + (lane & 15);
                const float x = acc[m][n][reg] * 0.001953125f;  // /(32*16)
                const float s = 1.0f / (1.0f + __expf(-x));
                lAtt[row * 128 + col] = (char)(__float2int_rn(s * 254.f) - 127);
            }
    __syncthreads();
    {
        const uint4* lsrc = (const uint4*)lAtt;   // 1024 uint4, 8 per row
#pragma unroll
        for (int i = 0; i < 4; ++i) {
            const int idx = i * 256 + t;
            const int r   = idx >> 3;
            const int c16 = idx & 7;
            *(uint4*)(att8 + (size_t)(m0 + r) * 512 + n0 + c16 * 16) = lsrc[idx];
        }
    }
}

// ---------------------------------------------------------------------------
// G2 (i8): aug = (P @ memT8^T + 127*colsum) / (254*4096).
// BM=256 x BN=128, K-slice 128 i8 (4 steps), 48KB LDS, 512 thr = 8 waves.
// Blocks with (wg&7)==0 additionally compute topk for their 256 rows
// (32 rows/wave, u8 ballot radix-select) — att8 rows are L2-warm from this
// block's own staging; the work hides under other blocks' HBM writes.
// ---------------------------------------------------------------------------
__global__ __launch_bounds__(512, 4)
void g2_kernel(const char* __restrict__ att8,
               const char* __restrict__ memT8,
               const float* __restrict__ colsumF,
               float* __restrict__ aug,
               float* __restrict__ temporal) {
    __shared__ __align__(16) unsigned char smem[49152];
    const int t    = threadIdx.x;
    const int lane = t & 63;
    const int wid  = t >> 6;      // 0..7
    const int wr   = wid >> 1;    // 0..3
    const int wc   = wid & 1;     // 0..1
    const int wg = (blockIdx.x & 7) * 128 + (blockIdx.x >> 3);
    const int m0 = (wg >> 3) * 256;
    const int n0 = (wg & 7) * 128;

    i32x4 zero = {0, 0, 0, 0};
    i32x4 acc[4][4];
#pragma unroll
    for (int m = 0; m < 4; ++m)
#pragma unroll
        for (int n = 0; n < 4; ++n) acc[m][n] = zero;

    const int srcoff = (((lane & 7) ^ (lane >> 3)) & 7) * 16;
    const char* aS = att8  + (size_t)(m0 + wid * 32 + (lane >> 3)) * 512 + srcoff;
    const char* bS = memT8 + (size_t)(n0 + wid * 16 + (lane >> 3)) * 512 + srcoff;

    const int q = lane >> 4;

    for (int tt = 0; tt < 4; ++tt) {
        {
            unsigned char* da = smem + wid * 4096 + lane * 16;
            unsigned char* db = smem + 32768 + wid * 2048 + lane * 16;
            const char* sa = aS + tt * 128;
            const char* sb = bS + tt * 128;
            GLDS16(sa,            da);
            GLDS16(sa +  8 * 512, da + 1024);
            GLDS16(sa + 16 * 512, da + 2048);
            GLDS16(sa + 24 * 512, da + 3072);
            GLDS16(sb,            db);
            GLDS16(sb +  8 * 512, db + 1024);
        }
        __syncthreads();
#pragma unroll
        for (int kk = 0; kk < 2; ++kk) {
            const int c16 = kk * 4 + q;
            i32x4 af[4], bfr[4];
#pragma unroll
            for (int m = 0; m < 4; ++m) {
                const int row = wr * 64 + m * 16 + (lane & 15);
                af[m] = *(const i32x4*)(smem + row * 128 + ((c16 ^ (row & 7)) << 4));
            }
#pragma unroll
            for (int n = 0; n < 4; ++n) {
                const int col = wc * 64 + n * 16 + (lane & 15);
                bfr[n] = *(const i32x4*)(smem + 32768 + col * 128 + ((c16 ^ (col & 7)) << 4));
            }
#pragma unroll
            for (int m = 0; m < 4; ++m)
#pragma unroll
                for (int n = 0; n < 4; ++n)
                    acc[m][n] = __builtin_amdgcn_mfma_i32_16x16x64_i8(
                        af[m], bfr[n], acc[m][n], 0, 0, 0);
        }
        __syncthreads();
    }

    const float kscale = 1.0f / (254.0f * 4096.0f);
#pragma unroll
    for (int m = 0; m < 4; ++m)
#pragma unroll
        for (int n = 0; n < 4; ++n)
#pragma unroll
            for (int reg = 0; reg < 4; ++reg) {
                const int row = m0 + wr * 64 + m * 16 + (lane >> 4) * 4 + reg;
                const int col = n0 + wc * 64 + n * 16 + (lane & 15);
                aug[(size_t)row * DIM + col] =
                    ((float)acc[m][n][reg] + 127.0f * colsumF[col]) * kscale;
            }

    // ---- fused topk: one block per m-panel (wg&7 == 0), 32 rows per wave
    if ((wg & 7) == 0) {
        for (int ri = 0; ri < 32; ++ri) {
            const int row = m0 + wid * 32 + ri;
            const uint2 rv = *(const uint2*)(att8 + (size_t)row * 512 + lane * 8);
            uint32_t u[8];
#pragma unroll
            for (int j = 0; j < 4; ++j) {
                u[j]     = (((rv.x >> (8 * j)) & 0xFFu) + 127u) & 0xFFu;
                u[j + 4] = (((rv.y >> (8 * j)) & 0xFFu) + 127u) & 0xFFu;
            }
            uint32_t tc = 0;
#pragma unroll
            for (int b = 7; b >= 0; --b) {
                const uint32_t cand = tc | (1u << b);
                int c = 0;
#pragma unroll
                for (int j = 0; j < 8; ++j)
                    c += __popcll(__ballot(u[j] >= cand));
                if (c >= TOPK) tc = cand;
            }
            float sgt = 0.f; int cgt = 0;
#pragma unroll
            for (int j = 0; j < 8; ++j) {
                if (u[j] > tc) { sgt += (float)u[j]; cgt++; }
            }
#pragma unroll
            for (int off = 32; off >= 1; off >>= 1) {
                sgt += __shfl_xor(sgt, off);
                cgt += __shfl_xor(cgt, off);
            }
            if (lane == 0)
                temporal[row] = (sgt + (float)(TOPK - cgt) * (float)tc)
                              * (1.0f / (254.0f * 33.0f));
        }
    }
}

// ---------------------------------------------------------------------------
extern "C" void kernel_launch(void* const* d_in, const int* in_sizes, int n_in,
                              void* d_out, int out_size, void* d_ws, size_t ws_size,
                              hipStream_t stream) {
    const float* data = (const float*)d_in[0];   // [16,2048,1024]
    const float* mem  = (const float*)d_in[1];   // [512,1024]
    float* temporal = (float*)d_out;             // [32768]
    float* aug      = (float*)d_out + M_TOTAL;   // [32768,1024] fp32 (128MB)

    uchar_t* memF8  = (uchar_t*)d_ws;                        // 512KB e4m3 x16
    char*    memT8  = (char*)(memF8 + (size_t)NUMS * DIM);   // 512KB i8 x4096
    float*   colsumF= (float*)(memT8 + (size_t)DIM * NUMS);  // 4KB
    char*    attw8  = (char*)(colsumF + DIM);                // 16MB i8 codes
    uchar_t* dataF8 = (uchar_t*)aug;                         // 32MB, pre-g2

    cvtprep_kernel<<<2560, 256, 0, stream>>>(data, mem, dataF8, memF8, memT8);
    g1_kernel<<<1024 + 4, 256, 0, stream>>>(dataF8, memF8, memT8, colsumF, attw8);
    g2_kernel<<<(M_TOTAL / 256) * (DIM / 128), 512, 0, stream>>>(attw8, memT8, colsumF, aug, temporal);
}

// Round 21
// 127.423 us; speedup vs baseline: 1.3899x; 1.3899x over previous
//
#include <hip/hip_runtime.h>
#include <stdint.h>

#define M_TOTAL 32768   // B*T
#define NUMS    512
#define DIM     1024
#define TOPK    33

typedef __bf16 bf16_t;
typedef float  f32x4  __attribute__((ext_vector_type(4)));
typedef int    i32x4  __attribute__((ext_vector_type(4)));
typedef unsigned short ushort_t;
typedef unsigned char  uchar_t;

__device__ __forceinline__ uint32_t pk4_fp8(float a, float b, float c, float d) {
    uint32_t w = 0;
    w = __builtin_amdgcn_cvt_pk_fp8_f32(a, b, w, false);
    w = __builtin_amdgcn_cvt_pk_fp8_f32(c, d, w, true);
    return w;
}
__device__ __forceinline__ int q12(float w) {   // round(w*4096), clamp +-127
    int v = __float2int_rn(w * 4096.f);
    return v > 127 ? 127 : (v < -127 ? -127 : v);
}

#define GLDS16(g, l) __builtin_amdgcn_global_load_lds( \
    (const __attribute__((address_space(1))) void*)(g), \
    (__attribute__((address_space(3))) void*)(l), 16, 0, 0)

// ---------------------------------------------------------------------------
// cvtprep: blocks 0..511: mem fp32 -> memF8 e4m3 (x16) + memT8 i8 (x4096,
//   transposed), dispatched first so the LDS-transpose overlaps the stream.
// blocks 512..2559: data fp32 -> dataF8 e4m3 (XCD-aligned writes).
// ---------------------------------------------------------------------------
__global__ __launch_bounds__(256)
void cvtprep_kernel(const float* __restrict__ data, const float* __restrict__ mem,
                    uchar_t* __restrict__ dataF8, uchar_t* __restrict__ memF8,
                    char* __restrict__ memT8) {
    __shared__ float tile[32][33];
    const int bid = blockIdx.x;
    const int t   = threadIdx.x;
    if (bid < 512) {
        const int bi = bid & 15;       // k-block (NUMS/32)
        const int bj = bid >> 4;       // d-block (DIM/32)
        const int r  = t >> 3;
        const int c4 = (t & 7) * 4;
        const float4 v = *(const float4*)(mem + (size_t)(bi * 32 + r) * DIM + bj * 32 + c4);
        *(uint32_t*)(memF8 + (size_t)(bi * 32 + r) * DIM + bj * 32 + c4) =
            pk4_fp8(v.x * 16.f, v.y * 16.f, v.z * 16.f, v.w * 16.f);
        tile[r][c4 + 0] = v.x; tile[r][c4 + 1] = v.y;
        tile[r][c4 + 2] = v.z; tile[r][c4 + 3] = v.w;
        __syncthreads();
        const int q0 = q12(tile[c4 + 0][r]);
        const int q1 = q12(tile[c4 + 1][r]);
        const int q2 = q12(tile[c4 + 2][r]);
        const int q3 = q12(tile[c4 + 3][r]);
        char4 o; o.x = (char)q0; o.y = (char)q1; o.z = (char)q2; o.w = (char)q3;
        *(char4*)(memT8 + (size_t)(bj * 32 + r) * NUMS + bi * 32 + c4) = o;
    } else {
        const int db = bid - 512;
        const int x = db & 7;          // XCD
        const int j = db >> 3;         // 0..255
        size_t i = ((size_t)x * 4096 + (size_t)j * 16) * DIM + t * 8;
#pragma unroll
        for (int it = 0; it < 8; ++it, i += 2048) {
            const float4 v0 = *(const float4*)(data + i);
            const float4 v1 = *(const float4*)(data + i + 4);
            uint2 pk;
            pk.x = pk4_fp8(v0.x, v0.y, v0.z, v0.w);
            pk.y = pk4_fp8(v1.x, v1.y, v1.z, v1.w);
            *(uint2*)(dataF8 + i) = pk;
        }
    }
}

// ---------------------------------------------------------------------------
// G1 (fp8): att = sigmoid(dataF8 @ memF8^T / 512) -> i8 code att*254-127.
// 128x128 tile, K-slice 128 fp8 (8 steps), double-buffered 64KB LDS with
// counted vmcnt: STAGE(t+1) -> vmcnt(8) -> barrier -> COMP(t) -> barrier.
// 256 thr = 4 waves (2x2), wave tile 64x64, 2 blocks/CU. (Best measured.)
// ---------------------------------------------------------------------------
__global__ __launch_bounds__(256, 2)
void g1_kernel(const uchar_t* __restrict__ dataF8,
               const uchar_t* __restrict__ memF8,
               char* __restrict__ att8) {
    __shared__ __align__(16) unsigned char smem[65536];
    const int t    = threadIdx.x;
    const int lane = t & 63;
    const int wid  = t >> 6;
    const int wr   = wid >> 1;
    const int wc   = wid & 1;
    const int wg = (blockIdx.x & 7) * 128 + (blockIdx.x >> 3);
    const int m0 = (wg >> 2) * 128;
    const int n0 = (wg & 3) * 128;

    f32x4 zero = {0.f, 0.f, 0.f, 0.f};
    f32x4 acc[4][4];
#pragma unroll
    for (int m = 0; m < 4; ++m)
#pragma unroll
        for (int n = 0; n < 4; ++n) acc[m][n] = zero;

    const int srcoff = (((lane & 7) ^ (lane >> 3)) & 7) * 16;
    const uchar_t* aS = dataF8 + (size_t)(m0 + wid * 32 + (lane >> 3)) * DIM + srcoff;
    const uchar_t* bS = memF8  + (size_t)(n0 + wid * 32 + (lane >> 3)) * DIM + srcoff;

    const int q  = lane >> 4;
    const int o8 = (q & 1) * 8;

#define G1_STAGE(TT_, BOFF_) {                                                  \
        unsigned char* da = smem + (BOFF_) + wid * 4096 + lane * 16;            \
        unsigned char* db = da + 16384;                                         \
        const uchar_t* sa = aS + (TT_) * 128;                                   \
        const uchar_t* sb = bS + (TT_) * 128;                                   \
        GLDS16(sa,            da);        GLDS16(sb,            db);            \
        GLDS16(sa +  8 * DIM, da + 1024); GLDS16(sb +  8 * DIM, db + 1024);     \
        GLDS16(sa + 16 * DIM, da + 2048); GLDS16(sb + 16 * DIM, db + 2048);     \
        GLDS16(sa + 24 * DIM, da + 3072); GLDS16(sb + 24 * DIM, db + 3072); }

#define G1_COMP(BOFF_)                                                          \
    _Pragma("unroll") for (int ki = 0; ki < 4; ++ki) {                          \
        const int c16 = ki * 2 + (q >> 1);                                      \
        long af[4], bfr[4];                                                     \
        _Pragma("unroll") for (int m = 0; m < 4; ++m) {                         \
            const int row = wr * 64 + m * 16 + (lane & 15);                     \
            af[m] = *(const long*)(smem + (BOFF_) + row * 128                   \
                    + ((c16 ^ (row & 7)) << 4) + o8);                           \
        }                                                                       \
        _Pragma("unroll") for (int n = 0; n < 4; ++n) {                         \
            const int col = wc * 64 + n * 16 + (lane & 15);                     \
            bfr[n] = *(const long*)(smem + (BOFF_) + 16384 + col * 128          \
                    + ((c16 ^ (col & 7)) << 4) + o8);                           \
        }                                                                       \
        _Pragma("unroll") for (int m = 0; m < 4; ++m)                           \
            _Pragma("unroll") for (int n = 0; n < 4; ++n)                       \
                acc[m][n] = __builtin_amdgcn_mfma_f32_16x16x32_fp8_fp8(         \
                    af[m], bfr[n], acc[m][n], 0, 0, 0);                         \
    }

    G1_STAGE(0, 0)
    for (int tt = 0; tt < 8; ++tt) {
        if (tt < 7) {
            if ((tt & 1) == 0) G1_STAGE(tt + 1, 32768)
            else               G1_STAGE(tt + 1, 0)
            asm volatile("s_waitcnt vmcnt(8)" ::: "memory");
        } else {
            asm volatile("s_waitcnt vmcnt(0)" ::: "memory");
        }
        __builtin_amdgcn_s_barrier();
        __builtin_amdgcn_sched_barrier(0);
        __builtin_amdgcn_s_setprio(1);
        if ((tt & 1) == 0) G1_COMP(0)
        else               G1_COMP(32768)
        __builtin_amdgcn_s_setprio(0);
        __builtin_amdgcn_s_barrier();
    }
#undef G1_STAGE
#undef G1_COMP

    // ---- epilogue: sigmoid(acc/512) -> i8 codes, tile [128][128] in LDS
    char* lAtt = (char*)smem;
#pragma unroll
    for (int m = 0; m < 4; ++m)
#pragma unroll
        for (int n = 0; n < 4; ++n)
#pragma unroll
            for (int reg = 0; reg < 4; ++reg) {
                const int row = wr * 64 + m * 16 + (lane >> 4) * 4 + reg;
                const int col = wc * 64 + n * 16 + (lane & 15);
                const float x = acc[m][n][reg] * 0.001953125f;  // /(32*16)
                const float s = 1.0f / (1.0f + __expf(-x));
                lAtt[row * 128 + col] = (char)(__float2int_rn(s * 254.f) - 127);
            }
    __syncthreads();
    {
        const uint4* lsrc = (const uint4*)lAtt;   // 1024 uint4, 8 per row
#pragma unroll
        for (int i = 0; i < 4; ++i) {
            const int idx = i * 256 + t;
            const int r   = idx >> 3;
            const int c16 = idx & 7;
            *(uint4*)(att8 + (size_t)(m0 + r) * 512 + n0 + c16 * 16) = lsrc[idx];
        }
    }
}

// ---------------------------------------------------------------------------
// topk (+colsum fold): blocks 0..4095: temporal via u8 ballot radix-select,
// 2 rows/wave. blocks 4096..4099: colsumF[d] = sum_k memT8[d][k].
// ---------------------------------------------------------------------------
__global__ __launch_bounds__(256, 8)
void topk_kernel(const char* __restrict__ att8,
                 const char* __restrict__ memT8,
                 float* __restrict__ colsumF,
                 float* __restrict__ temporal) {
    const int t = threadIdx.x;
    if (blockIdx.x >= 4096) {
        const int d = (blockIdx.x - 4096) * 256 + t;   // 0..1023
        const int* p = (const int*)(memT8 + (size_t)d * NUMS);
        int s = 0;
#pragma unroll
        for (int i = 0; i < 128; ++i) {
            const int w = p[i];
            s += (int)(char)(w) + (int)(char)(w >> 8)
               + (int)(char)(w >> 16) + (int)(char)(w >> 24);
        }
        colsumF[d] = (float)s;
        return;
    }
    const int lane = t & 63;
    const int wid  = t >> 6;
    const int base = blockIdx.x * 8 + wid * 2;

    for (int ri = 0; ri < 2; ++ri) {
        const int row = base + ri;
        const uint2 rv = *(const uint2*)(att8 + (size_t)row * 512 + lane * 8);
        uint32_t u[8];
#pragma unroll
        for (int j = 0; j < 4; ++j) {
            u[j]     = (((rv.x >> (8 * j)) & 0xFFu) + 127u) & 0xFFu;
            u[j + 4] = (((rv.y >> (8 * j)) & 0xFFu) + 127u) & 0xFFu;
        }
        uint32_t tc = 0;
#pragma unroll
        for (int b = 7; b >= 0; --b) {
            const uint32_t cand = tc | (1u << b);
            int c = 0;
#pragma unroll
            for (int j = 0; j < 8; ++j)
                c += __popcll(__ballot(u[j] >= cand));
            if (c >= TOPK) tc = cand;
        }
        float sgt = 0.f; int cgt = 0;
#pragma unroll
        for (int j = 0; j < 8; ++j) {
            if (u[j] > tc) { sgt += (float)u[j]; cgt++; }
        }
#pragma unroll
        for (int off = 32; off >= 1; off >>= 1) {
            sgt += __shfl_xor(sgt, off);
            cgt += __shfl_xor(cgt, off);
        }
        if (lane == 0)
            temporal[row] = (sgt + (float)(TOPK - cgt) * (float)tc)
                          * (1.0f / (254.0f * 33.0f));
    }
}

// ---------------------------------------------------------------------------
// G2 (i8): aug = (P @ memT8^T + 127*colsum) / (254*4096).
// BM=256 x BN=128, K-slice 128 i8 (4 steps), 48KB LDS (A 32KB, B 16KB),
// 512 thr = 8 waves (4m x 2n), wave tile 64x64. (Best measured.)
// ---------------------------------------------------------------------------
__global__ __launch_bounds__(512, 4)
void g2_kernel(const char* __restrict__ att8,
               const char* __restrict__ memT8,
               const float* __restrict__ colsumF,
               float* __restrict__ aug) {
    __shared__ __align__(16) unsigned char smem[49152];
    const int t    = threadIdx.x;
    const int lane = t & 63;
    const int wid  = t >> 6;      // 0..7
    const int wr   = wid >> 1;    // 0..3
    const int wc   = wid & 1;     // 0..1
    const int wg = (blockIdx.x & 7) * 128 + (blockIdx.x >> 3);
    const int m0 = (wg >> 3) * 256;
    const int n0 = (wg & 7) * 128;

    i32x4 zero = {0, 0, 0, 0};
    i32x4 acc[4][4];
#pragma unroll
    for (int m = 0; m < 4; ++m)
#pragma unroll
        for (int n = 0; n < 4; ++n) acc[m][n] = zero;

    const int srcoff = (((lane & 7) ^ (lane >> 3)) & 7) * 16;
    const char* aS = att8  + (size_t)(m0 + wid * 32 + (lane >> 3)) * 512 + srcoff;
    const char* bS = memT8 + (size_t)(n0 + wid * 16 + (lane >> 3)) * 512 + srcoff;

    const int q = lane >> 4;

    for (int tt = 0; tt < 4; ++tt) {
        {
            unsigned char* da = smem + wid * 4096 + lane * 16;
            unsigned char* db = smem + 32768 + wid * 2048 + lane * 16;
            const char* sa = aS + tt * 128;
            const char* sb = bS + tt * 128;
            GLDS16(sa,            da);
            GLDS16(sa +  8 * 512, da + 1024);
            GLDS16(sa + 16 * 512, da + 2048);
            GLDS16(sa + 24 * 512, da + 3072);
            GLDS16(sb,            db);
            GLDS16(sb +  8 * 512, db + 1024);
        }
        __syncthreads();
#pragma unroll
        for (int kk = 0; kk < 2; ++kk) {
            const int c16 = kk * 4 + q;
            i32x4 af[4], bfr[4];
#pragma unroll
            for (int m = 0; m < 4; ++m) {
                const int row = wr * 64 + m * 16 + (lane & 15);
                af[m] = *(const i32x4*)(smem + row * 128 + ((c16 ^ (row & 7)) << 4));
            }
#pragma unroll
            for (int n = 0; n < 4; ++n) {
                const int col = wc * 64 + n * 16 + (lane & 15);
                bfr[n] = *(const i32x4*)(smem + 32768 + col * 128 + ((c16 ^ (col & 7)) << 4));
            }
#pragma unroll
            for (int m = 0; m < 4; ++m)
#pragma unroll
                for (int n = 0; n < 4; ++n)
                    acc[m][n] = __builtin_amdgcn_mfma_i32_16x16x64_i8(
                        af[m], bfr[n], acc[m][n], 0, 0, 0);
        }
        __syncthreads();
    }

    const float kscale = 1.0f / (254.0f * 4096.0f);
#pragma unroll
    for (int m = 0; m < 4; ++m)
#pragma unroll
        for (int n = 0; n < 4; ++n)
#pragma unroll
            for (int reg = 0; reg < 4; ++reg) {
                const int row = m0 + wr * 64 + m * 16 + (lane >> 4) * 4 + reg;
                const int col = n0 + wc * 64 + n * 16 + (lane & 15);
                aug[(size_t)row * DIM + col] =
                    ((float)acc[m][n][reg] + 127.0f * colsumF[col]) * kscale;
            }
}

// ---------------------------------------------------------------------------
extern "C" void kernel_launch(void* const* d_in, const int* in_sizes, int n_in,
                              void* d_out, int out_size, void* d_ws, size_t ws_size,
                              hipStream_t stream) {
    const float* data = (const float*)d_in[0];   // [16,2048,1024]
    const float* mem  = (const float*)d_in[1];   // [512,1024]
    float* temporal = (float*)d_out;             // [32768]
    float* aug      = (float*)d_out + M_TOTAL;   // [32768,1024] fp32 (128MB)

    uchar_t* memF8  = (uchar_t*)d_ws;                        // 512KB e4m3 x16
    char*    memT8  = (char*)(memF8 + (size_t)NUMS * DIM);   // 512KB i8 x4096
    float*   colsumF= (float*)(memT8 + (size_t)DIM * NUMS);  // 4KB
    char*    attw8  = (char*)(colsumF + DIM);                // 16MB i8 codes
    uchar_t* dataF8 = (uchar_t*)aug;                         // 32MB, pre-g2

    cvtprep_kernel<<<2560, 256, 0, stream>>>(data, mem, dataF8, memF8, memT8);
    g1_kernel<<<(M_TOTAL / 128) * (NUMS / 128), 256, 0, stream>>>(dataF8, memF8, attw8);
    topk_kernel<<<M_TOTAL / 8 + 4, 256, 0, stream>>>(attw8, memT8, colsumF, temporal);
    g2_kernel<<<(M_TOTAL / 256) * (DIM / 128), 512, 0, stream>>>(attw8, memT8, colsumF, aug);
}